// Round 2
// baseline (776.432 us; speedup 1.0000x reference)
//
#include <hip/hip_runtime.h>
#include <stdint.h>
#include <stddef.h>

typedef __bf16 bft;
typedef __bf16 bf16x4 __attribute__((ext_vector_type(4)));
typedef __bf16 bf16x8 __attribute__((ext_vector_type(8)));
typedef float f32x4 __attribute__((ext_vector_type(4)));

#define NH 12
#define HD 64
#define SEQ 1025
#define NB 32
#define DMODEL 768
#define MROWS (NB * SEQ)   /* 32800 */
#define BHN (NB * NH)      /* 384 */
#define FROWS (BHN * SEQ)  /* 393600 */

__device__ __forceinline__ void gl_lds16(const void* g, void* l) {
  __builtin_amdgcn_global_load_lds(
      (const __attribute__((address_space(1))) void*)g,
      (__attribute__((address_space(3))) void*)l, 16, 0, 0);
}

// ---------------- K0: fp32 -> bf16 cast ----------------
__global__ __launch_bounds__(256) void k_cast(
    const float* __restrict__ S, bft* __restrict__ D, int n4) {
  int i = blockIdx.x * 256 + threadIdx.x;
  if (i < n4) {
    f32x4 v = *(const f32x4*)(S + (size_t)i * 4);
    bf16x4 o;
    o[0] = (bft)v[0]; o[1] = (bft)v[1]; o[2] = (bft)v[2]; o[3] = (bft)v[3];
    *(bf16x4*)(D + (size_t)i * 4) = o;
  }
}

// ---------------- K1: QKV GEMM (M=32800, N=2304, K=768) + fused RoPE ----------------
__global__ __launch_bounds__(256) void k_qkv_gemm(
    const bft* __restrict__ X, const bft* __restrict__ W,
    const float* __restrict__ FC, const float* __restrict__ FS,
    bft* __restrict__ QKV) {
  __shared__ bft sA[128 * 64];
  __shared__ bft sB[128 * 64];
  const int tid = threadIdx.x;
  const int lane = tid & 63;
  const int lm = lane & 15;
  const int quad = lane >> 4;
  const int wid = tid >> 6;
  const int wm = (wid & 1) << 6;
  const int wn = (wid >> 1) << 6;
  const int m0 = blockIdx.x * 128;
  const int n0 = blockIdx.y * 128;

  f32x4 acc[4][4] = {};

  for (int kt = 0; kt < DMODEL; kt += 64) {
#pragma unroll
    for (int it = 0; it < 4; it++) {
      int c = it * 256 + tid;
      int row = c >> 3;
      int col = (c & 7) << 3;
      int ar = m0 + row;
      if (ar >= MROWS) ar = MROWS - 1;
      gl_lds16(X + (size_t)ar * DMODEL + kt + col, sA + c * 8);
      gl_lds16(W + (size_t)(n0 + row) * DMODEL + kt + col, sB + c * 8);
    }
    __syncthreads();
#pragma unroll
    for (int kk = 0; kk < 2; kk++) {
      bf16x8 af[4], bb[4];
#pragma unroll
      for (int i = 0; i < 4; i++)
        af[i] = *(const bf16x8*)(sA + (wm + i * 16 + lm) * 64 + kk * 32 + quad * 8);
#pragma unroll
      for (int j = 0; j < 4; j++)
        bb[j] = *(const bf16x8*)(sB + (wn + j * 16 + lm) * 64 + kk * 32 + quad * 8);
#pragma unroll
      for (int i = 0; i < 4; i++)
#pragma unroll
        for (int j = 0; j < 4; j++)
          acc[i][j] = __builtin_amdgcn_mfma_f32_16x16x32_bf16(af[i], bb[j], acc[i][j], 0, 0, 0);
    }
    __syncthreads();
  }

  // epilogue: RoPE (pairs are adjacent lanes -> shfl_xor 1) + scatter to (s,b,h,n,d)
#pragma unroll
  for (int i = 0; i < 4; i++) {
#pragma unroll
    for (int r = 0; r < 4; r++) {
      int m = m0 + wm + i * 16 + quad * 4 + r;
      int b = m / SEQ;
      int n = m - b * SEQ;
#pragma unroll
      for (int j = 0; j < 4; j++) {
        float v = acc[i][j][r];
        float pv = __shfl_xor(v, 1);
        int g = n0 + wn + j * 16 + lm;
        int s = g / DMODEL;
        int rem = g - s * DMODEL;
        int h = rem >> 6;
        int d = rem & 63;
        float ov = v;
        if (s < 2 && n >= 1) {
          int fj = d >> 1;
          float cc = FC[(n - 1) * 32 + fj];
          float ss = FS[(n - 1) * 32 + fj];
          ov = (d & 1) ? (pv * ss + v * cc) : (v * cc - pv * ss);
        }
        if (m < MROWS) {
          QKV[((((size_t)s * NB + b) * NH + h) * SEQ + n) * HD + d] = (bft)ov;
        }
      }
    }
  }
}

// ---------------- K2: feature map GEMM (M=393600, N=64, K=64), in-place ----------------
__global__ __launch_bounds__(256) void k_feat(
    const bft* __restrict__ T, const bft* __restrict__ P, bft* __restrict__ F) {
  __shared__ bft sA[128 * 64];
  __shared__ bft sB[64 * 64];
  const int tid = threadIdx.x;
  const int lane = tid & 63;
  const int lm = lane & 15;
  const int quad = lane >> 4;
  const int wid = tid >> 6;
  const int m0 = blockIdx.x * 128;

#pragma unroll
  for (int it = 0; it < 4; it++) {
    int c = it * 256 + tid;
    gl_lds16(T + (size_t)m0 * 64 + c * 8, sA + c * 8);
  }
#pragma unroll
  for (int it = 0; it < 2; it++) {
    int c = it * 256 + tid;
    gl_lds16(P + c * 8, sB + c * 8);
  }
  __syncthreads();

  f32x4 acc[2][4] = {};
#pragma unroll
  for (int kk = 0; kk < 2; kk++) {
    bf16x8 af[2], bb[4];
#pragma unroll
    for (int i = 0; i < 2; i++)
      af[i] = *(const bf16x8*)(sA + (wid * 32 + i * 16 + lm) * 64 + kk * 32 + quad * 8);
#pragma unroll
    for (int j = 0; j < 4; j++)
      bb[j] = *(const bf16x8*)(sB + (j * 16 + lm) * 64 + kk * 32 + quad * 8);
#pragma unroll
    for (int i = 0; i < 2; i++)
#pragma unroll
      for (int j = 0; j < 4; j++)
        acc[i][j] = __builtin_amdgcn_mfma_f32_16x16x32_bf16(af[i], bb[j], acc[i][j], 0, 0, 0);
  }

#pragma unroll
  for (int i = 0; i < 2; i++) {
#pragma unroll
    for (int r = 0; r < 4; r++) {
      int row = m0 + wid * 32 + i * 16 + quad * 4 + r;
#pragma unroll
      for (int j = 0; j < 4; j++) {
        int col = j * 16 + lm;
        float v = acc[i][j][r] * 0.35355339f;  // 64^-0.25
        v = fmaxf(v, 0.f) + 1e-6f;
        F[(size_t)row * 64 + col] = (bft)v;
      }
    }
  }
}

// ---------------- K3: context = kf^T @ v (per bh), fused k_sum ----------------
__global__ __launch_bounds__(256) void k_context(
    const bft* __restrict__ KF, const bft* __restrict__ V,
    float* __restrict__ CTX, float* __restrict__ KSUM) {
  __shared__ float skf[8 * 64];
  __shared__ float sv[8 * 64];
  const int tid = threadIdx.x;
  const int bh = blockIdx.x;
  const bft* kf = KF + (size_t)bh * SEQ * HD;
  const bft* vv = V + (size_t)bh * SEQ * HD;
  const int tok = tid >> 6;
  const int dd = tid & 63;
  const int f0 = (tid >> 4) * 4;
  const int e0 = (tid & 15) * 4;

  float acc[4][4] = {};
  float ks[4] = {0.f, 0.f, 0.f, 0.f};

  for (int n0 = 0; n0 < SEQ; n0 += 8) {
#pragma unroll
    for (int half = 0; half < 2; half++) {
      int tk = tok + half * 4;
      int n = n0 + tk;
      bool ok = n < SEQ;
      skf[tk * 64 + dd] = ok ? (float)kf[(size_t)n * 64 + dd] : 0.f;
      sv[tk * 64 + dd] = ok ? (float)vv[(size_t)n * 64 + dd] : 0.f;
    }
    __syncthreads();
#pragma unroll
    for (int t4 = 0; t4 < 8; t4++) {
      f32x4 kq = *(const f32x4*)(skf + t4 * 64 + f0);
      f32x4 vq = *(const f32x4*)(sv + t4 * 64 + e0);
#pragma unroll
      for (int i = 0; i < 4; i++) {
        ks[i] += kq[i];
#pragma unroll
        for (int j = 0; j < 4; j++) acc[i][j] += kq[i] * vq[j];
      }
    }
    __syncthreads();
  }

  float* cp = CTX + (size_t)bh * 4096;
#pragma unroll
  for (int i = 0; i < 4; i++)
#pragma unroll
    for (int j = 0; j < 4; j++) cp[(f0 + i) * 64 + e0 + j] = acc[i][j];
  if (e0 == 0) {
#pragma unroll
    for (int i = 0; i < 4; i++) KSUM[bh * 64 + f0 + i] = ks[i];
  }
}

// ---------------- K4: out = (qf @ ctx) * (1/(qf . ksum)), write attn(b,n,h*64+e) ----------------
__global__ __launch_bounds__(256) void k_qside(
    const bft* __restrict__ QF, const float* __restrict__ CTX,
    const float* __restrict__ KSUM, bft* __restrict__ ATTN) {
  __shared__ float sqf[128 * 65];
  __shared__ float sctx[64 * 64];
  __shared__ float sks[64];
  const int tid = threadIdx.x;
  const int bh = blockIdx.x;
  const int n0 = blockIdx.y * 128;
  const int ntok = (SEQ - n0 < 128) ? (SEQ - n0) : 128;
  const bft* qf = QF + ((size_t)bh * SEQ + n0) * HD;

#pragma unroll
  for (int i = 0; i < 4; i++) {
    int idx = i * 1024 + tid * 4;
    *(f32x4*)(sctx + idx) = *(const f32x4*)(CTX + (size_t)bh * 4096 + idx);
  }
  if (tid < 64) sks[tid] = KSUM[bh * 64 + tid];

#pragma unroll
  for (int it = 0; it < 4; it++) {
    int c = it * 256 + tid;
    int row = c >> 3;
    int col = (c & 7) << 3;
    if (row < ntok) {
      bf16x8 t = *(const bf16x8*)(qf + (size_t)row * 64 + col);
#pragma unroll
      for (int e = 0; e < 8; e++) sqf[row * 65 + col + e] = (float)t[e];
    } else {
#pragma unroll
      for (int e = 0; e < 8; e++) sqf[row * 65 + col + e] = 0.f;
    }
  }
  __syncthreads();

  const int e0 = (tid & 7) * 8;
  const int t0 = (tid >> 3) * 4;
  float acc[4][8] = {};
  float den[4] = {0.f, 0.f, 0.f, 0.f};
#pragma unroll 8
  for (int f = 0; f < 64; f++) {
    float kv = sks[f];
    f32x4 c0 = *(const f32x4*)(sctx + f * 64 + e0);
    f32x4 c1 = *(const f32x4*)(sctx + f * 64 + e0 + 4);
#pragma unroll
    for (int tk = 0; tk < 4; tk++) {
      float qv = sqf[(t0 + tk) * 65 + f];
      den[tk] += qv * kv;
      acc[tk][0] += qv * c0[0];
      acc[tk][1] += qv * c0[1];
      acc[tk][2] += qv * c0[2];
      acc[tk][3] += qv * c0[3];
      acc[tk][4] += qv * c1[0];
      acc[tk][5] += qv * c1[1];
      acc[tk][6] += qv * c1[2];
      acc[tk][7] += qv * c1[3];
    }
  }
  const int b = bh / NH;
  const int h = bh - b * NH;
#pragma unroll
  for (int tk = 0; tk < 4; tk++) {
    int n = n0 + t0 + tk;
    if (n < SEQ) {
      float di = 1.0f / den[tk];
      bf16x8 o;
#pragma unroll
      for (int e = 0; e < 8; e++) o[e] = (bft)(acc[tk][e] * di);
      *(bf16x8*)(ATTN + ((size_t)(b * SEQ + n)) * DMODEL + h * 64 + e0) = o;
    }
  }
}

// ---------------- K5: out GEMM (M=32800, N=768, K=768) + bias, fp32 out ----------------
__global__ __launch_bounds__(256) void k_out_gemm(
    const bft* __restrict__ A, const bft* __restrict__ W,
    const float* __restrict__ BIAS, float* __restrict__ OUT) {
  __shared__ bft sA[128 * 64];
  __shared__ bft sB[128 * 64];
  const int tid = threadIdx.x;
  const int lane = tid & 63;
  const int lm = lane & 15;
  const int quad = lane >> 4;
  const int wid = tid >> 6;
  const int wm = (wid & 1) << 6;
  const int wn = (wid >> 1) << 6;
  const int m0 = blockIdx.x * 128;
  const int n0 = blockIdx.y * 128;

  f32x4 acc[4][4] = {};

  for (int kt = 0; kt < DMODEL; kt += 64) {
#pragma unroll
    for (int it = 0; it < 4; it++) {
      int c = it * 256 + tid;
      int row = c >> 3;
      int col = (c & 7) << 3;
      int ar = m0 + row;
      if (ar >= MROWS) ar = MROWS - 1;
      gl_lds16(A + (size_t)ar * DMODEL + kt + col, sA + c * 8);
      gl_lds16(W + (size_t)(n0 + row) * DMODEL + kt + col, sB + c * 8);
    }
    __syncthreads();
#pragma unroll
    for (int kk = 0; kk < 2; kk++) {
      bf16x8 af[4], bb[4];
#pragma unroll
      for (int i = 0; i < 4; i++)
        af[i] = *(const bf16x8*)(sA + (wm + i * 16 + lm) * 64 + kk * 32 + quad * 8);
#pragma unroll
      for (int j = 0; j < 4; j++)
        bb[j] = *(const bf16x8*)(sB + (wn + j * 16 + lm) * 64 + kk * 32 + quad * 8);
#pragma unroll
      for (int i = 0; i < 4; i++)
#pragma unroll
        for (int j = 0; j < 4; j++)
          acc[i][j] = __builtin_amdgcn_mfma_f32_16x16x32_bf16(af[i], bb[j], acc[i][j], 0, 0, 0);
    }
    __syncthreads();
  }

#pragma unroll
  for (int i = 0; i < 4; i++) {
#pragma unroll
    for (int r = 0; r < 4; r++) {
      int m = m0 + wm + i * 16 + quad * 4 + r;
      if (m < MROWS) {
#pragma unroll
        for (int j = 0; j < 4; j++) {
          int g = n0 + wn + j * 16 + lm;
          OUT[(size_t)m * DMODEL + g] = acc[i][j][r] + BIAS[g];
        }
      }
    }
  }
}

extern "C" void kernel_launch(void* const* d_in, const int* in_sizes, int n_in,
                              void* d_out, int out_size, void* d_ws, size_t ws_size,
                              hipStream_t stream) {
  const float* x = (const float*)d_in[0];
  const float* wqkv = (const float*)d_in[1];
  const float* wout = (const float*)d_in[2];
  const float* bout = (const float*)d_in[3];
  const float* proj = (const float*)d_in[4];
  const float* fc = (const float*)d_in[5];
  const float* fs = (const float*)d_in[6];
  float* outp = (float*)d_out;

  // workspace layout (bytes, all 16B-aligned)
  char* ws = (char*)d_ws;
  const size_t xb_bytes = (size_t)MROWS * DMODEL * 2;               // 50,457,600
  const size_t qkv_bytes = (size_t)3 * BHN * SEQ * HD * 2;          // 151,142,400
  const size_t wqkvb_bytes = (size_t)3 * DMODEL * DMODEL * 2;       // 3,538,944
  const size_t woutb_bytes = (size_t)DMODEL * DMODEL * 2;           // 1,179,648
  const size_t projb_bytes = (size_t)HD * HD * 2;                   // 8,192
  const size_t ctx_bytes = (size_t)BHN * 64 * 64 * 4;               // 6,291,456

  bft* xb = (bft*)ws;                                    // bf16 x; dead after K1 -> reused as attn
  bft* qkvb = (bft*)(ws + xb_bytes);
  bft* wqkvb = (bft*)(ws + xb_bytes + qkv_bytes);
  bft* woutb = (bft*)(ws + xb_bytes + qkv_bytes + wqkvb_bytes);
  bft* projb = (bft*)(ws + xb_bytes + qkv_bytes + wqkvb_bytes + woutb_bytes);
  float* ctx = (float*)(ws + xb_bytes + qkv_bytes + wqkvb_bytes + woutb_bytes + projb_bytes);
  float* ksum = (float*)(ws + xb_bytes + qkv_bytes + wqkvb_bytes + woutb_bytes + projb_bytes + ctx_bytes);
  bft* attn = xb;  // alias: xb dead after K1; attn (50,380,800 B) <= xb region

  bft* qreg = qkvb;
  bft* kreg = qkvb + (size_t)BHN * SEQ * HD;
  bft* vreg = qkvb + (size_t)2 * BHN * SEQ * HD;

  dim3 blk(256);
  // casts
  k_cast<<<dim3((MROWS * DMODEL / 4 + 255) / 256), blk, 0, stream>>>(x, xb, MROWS * DMODEL / 4);
  k_cast<<<dim3((3 * DMODEL * DMODEL / 4 + 255) / 256), blk, 0, stream>>>(wqkv, wqkvb, 3 * DMODEL * DMODEL / 4);
  k_cast<<<dim3((DMODEL * DMODEL / 4 + 255) / 256), blk, 0, stream>>>(wout, woutb, DMODEL * DMODEL / 4);
  k_cast<<<dim3((HD * HD / 4 + 255) / 256), blk, 0, stream>>>(proj, projb, HD * HD / 4);

  k_qkv_gemm<<<dim3(257, 18), blk, 0, stream>>>(xb, wqkvb, fc, fs, qkvb);
  k_feat<<<dim3(FROWS / 128), blk, 0, stream>>>(qreg, projb, qreg);  // in-place qf
  k_feat<<<dim3(FROWS / 128), blk, 0, stream>>>(kreg, projb, kreg);  // in-place kf
  k_context<<<dim3(BHN), blk, 0, stream>>>(kreg, vreg, ctx, ksum);
  k_qside<<<dim3(BHN, 9), blk, 0, stream>>>(qreg, ctx, ksum, attn);
  k_out_gemm<<<dim3(257, 6), blk, 0, stream>>>(attn, woutb, bout, outp);
  (void)in_sizes; (void)n_in; (void)out_size; (void)ws_size;
}

// Round 3
// 747.871 us; speedup vs baseline: 1.0382x; 1.0382x over previous
//
#include <hip/hip_runtime.h>
#include <stdint.h>
#include <stddef.h>

typedef __bf16 bft;
typedef __bf16 bf16x4 __attribute__((ext_vector_type(4)));
typedef __bf16 bf16x8 __attribute__((ext_vector_type(8)));
typedef float f32x4 __attribute__((ext_vector_type(4)));

#define NH 12
#define HD 64
#define SEQ 1025
#define NB 32
#define DMODEL 768
#define MROWS (NB * SEQ)   /* 32800 */
#define BHN (NB * NH)      /* 384 */
#define CSPLIT 8
#define CCHUNK 129         /* ceil(1025/8) */

__device__ __forceinline__ void gl_lds16(const void* g, void* l) {
  __builtin_amdgcn_global_load_lds(
      (const __attribute__((address_space(1))) void*)g,
      (__attribute__((address_space(3))) void*)l, 16, 0, 0);
}

// ---------------- K0: fp32 -> bf16 cast ----------------
__global__ __launch_bounds__(256) void k_cast(
    const float* __restrict__ S, bft* __restrict__ D, int n4) {
  int i = blockIdx.x * 256 + threadIdx.x;
  if (i < n4) {
    f32x4 v = *(const f32x4*)(S + (size_t)i * 4);
    bf16x4 o;
    o[0] = (bft)v[0]; o[1] = (bft)v[1]; o[2] = (bft)v[2]; o[3] = (bft)v[3];
    *(bf16x4*)(D + (size_t)i * 4) = o;
  }
}

// ---------------- K1: QKV GEMM + fused RoPE + fused feature map ----------------
// grid (257, 18). y/6 = s (0=q,1=k,2=v). Columns 64-aligned to heads.
// LDS tiles XOR-swizzled: LDS slot cb holds global colblock cb^(row&7).
__global__ __launch_bounds__(256) void k_qkv_gemm(
    const bft* __restrict__ X, const bft* __restrict__ W,
    const bft* __restrict__ P,
    const float* __restrict__ FC, const float* __restrict__ FS,
    bft* __restrict__ QKV) {
  __shared__ __align__(16) bft sA[128 * 64];
  __shared__ __align__(16) bft sB[128 * 64];
  __shared__ __align__(16) bft sP[64 * 64];
  const int tid = threadIdx.x;
  const int lane = tid & 63;
  const int lm = lane & 15;
  const int quad = lane >> 4;
  const int wid = tid >> 6;
  const int wm = (wid & 1) << 6;
  const int wn = (wid >> 1) << 6;
  const int m0 = blockIdx.x * 128;
  const int n0 = blockIdx.y * 128;
  const int sw = lm & 7;
  const int o0 = (quad ^ sw) << 3;        // kk=0 swizzled col offset (elements)
  const int o1 = ((4 + quad) ^ sw) << 3;  // kk=1

  // stage projection (64x64) once, swizzled
#pragma unroll
  for (int it = 0; it < 2; it++) {
    int c = it * 256 + tid;
    int row = c >> 3;
    int col = ((c & 7) ^ (row & 7)) << 3;
    gl_lds16(P + row * 64 + col, sP + c * 8);
  }

  f32x4 acc[4][4] = {};

  for (int kt = 0; kt < DMODEL; kt += 64) {
#pragma unroll
    for (int it = 0; it < 4; it++) {
      int c = it * 256 + tid;
      int row = c >> 3;
      int col = ((c & 7) ^ (row & 7)) << 3;
      int ar = m0 + row;
      if (ar >= MROWS) ar = MROWS - 1;
      gl_lds16(X + (size_t)ar * DMODEL + kt + col, sA + c * 8);
      gl_lds16(W + (size_t)(n0 + row) * DMODEL + kt + col, sB + c * 8);
    }
    __syncthreads();
#pragma unroll
    for (int kk = 0; kk < 2; kk++) {
      const int off = (kk ? o1 : o0) + kk * 0;  // swizzled, kk encoded in o0/o1
      bf16x8 af[4], bb[4];
#pragma unroll
      for (int i = 0; i < 4; i++)
        af[i] = *(const bf16x8*)(sA + (wm + i * 16 + lm) * 64 + off);
#pragma unroll
      for (int j = 0; j < 4; j++)
        bb[j] = *(const bf16x8*)(sB + (wn + j * 16 + lm) * 64 + off);
#pragma unroll
      for (int i = 0; i < 4; i++)
#pragma unroll
        for (int j = 0; j < 4; j++)
          acc[i][j] = __builtin_amdgcn_mfma_f32_16x16x32_bf16(af[i], bb[j], acc[i][j], 0, 0, 0);
    }
    __syncthreads();
  }

  const int s = blockIdx.y / 6;                 // 0=q 1=k 2=v (uniform per block)
  const int h = ((n0 + wn) - s * DMODEL) >> 6;  // head (uniform per wave)

  if (s < 2) {
    // fused RoPE + feature map: wave-private scratch in sA (all waves past final barrier)
    bft* tt = sA + wid * (16 * 72);  // 16 rows x stride 72 bf16
#pragma unroll
    for (int i = 0; i < 4; i++) {
      // RoPE -> transpose tile to MFMA-A layout in LDS
#pragma unroll
      for (int r = 0; r < 4; r++) {
        int m = m0 + wm + i * 16 + quad * 4 + r;
        int b = m / SEQ;
        int n = m - b * SEQ;
#pragma unroll
        for (int j = 0; j < 4; j++) {
          float v = acc[i][j][r];
          float pv = __shfl_xor(v, 1);
          int d = j * 16 + lm;
          float ov = v;
          if (n >= 1) {
            int fj = d >> 1;
            float cc = FC[(n - 1) * 32 + fj];
            float ss = FS[(n - 1) * 32 + fj];
            ov = (d & 1) ? (pv * ss + v * cc) : (v * cc - pv * ss);
          }
          tt[(quad * 4 + r) * 72 + d] = (bft)ov;
        }
      }
      bf16x8 a0 = *(const bf16x8*)(tt + lm * 72 + quad * 8);
      bf16x8 a1 = *(const bf16x8*)(tt + lm * 72 + 32 + quad * 8);
#pragma unroll
      for (int j2 = 0; j2 < 4; j2++) {
        bf16x8 p0 = *(const bf16x8*)(sP + (j2 * 16 + lm) * 64 + o0);
        bf16x8 p1 = *(const bf16x8*)(sP + (j2 * 16 + lm) * 64 + o1);
        f32x4 fa = {0.f, 0.f, 0.f, 0.f};
        fa = __builtin_amdgcn_mfma_f32_16x16x32_bf16(a0, p0, fa, 0, 0, 0);
        fa = __builtin_amdgcn_mfma_f32_16x16x32_bf16(a1, p1, fa, 0, 0, 0);
        int jcol = j2 * 16 + lm;
#pragma unroll
        for (int r = 0; r < 4; r++) {
          int m = m0 + wm + i * 16 + quad * 4 + r;
          if (m < MROWS) {
            int b = m / SEQ;
            int n = m - b * SEQ;
            float v = fa[r] * 0.35355339f;  // 64^-0.25
            v = fmaxf(v, 0.f) + 1e-6f;
            QKV[((((size_t)s * NB + b) * NH + h) * SEQ + n) * HD + jcol] = (bft)v;
          }
        }
      }
    }
  } else {
    // v: plain scatter
#pragma unroll
    for (int i = 0; i < 4; i++) {
#pragma unroll
      for (int r = 0; r < 4; r++) {
        int m = m0 + wm + i * 16 + quad * 4 + r;
        if (m < MROWS) {
          int b = m / SEQ;
          int n = m - b * SEQ;
#pragma unroll
          for (int j = 0; j < 4; j++) {
            int d = j * 16 + lm;
            QKV[((((size_t)2 * NB + b) * NH + h) * SEQ + n) * HD + d] = (bft)acc[i][j][r];
          }
        }
      }
    }
  }
}

// ---------------- K3: context += kf^T @ v (seq-split, atomic), fused k_sum ----------------
__global__ __launch_bounds__(256) void k_context(
    const bft* __restrict__ KF, const bft* __restrict__ V,
    float* __restrict__ CTX, float* __restrict__ KSUM) {
  __shared__ float skf[16 * 64];
  __shared__ float sv[16 * 64];
  const int tid = threadIdx.x;
  const int bh = blockIdx.x;
  const int t_begin = blockIdx.y * CCHUNK;
  const int t_end = (t_begin + CCHUNK < SEQ) ? (t_begin + CCHUNK) : SEQ;
  const bft* kf = KF + (size_t)bh * SEQ * HD;
  const bft* vv = V + (size_t)bh * SEQ * HD;
  const int srow = tid >> 4;
  const int scol = (tid & 15) * 4;
  const int f0 = (tid >> 4) * 4;
  const int e0 = (tid & 15) * 4;

  float acc[4][4] = {};
  float ks[4] = {0.f, 0.f, 0.f, 0.f};

  for (int nt = t_begin; nt < t_end; nt += 16) {
    int n = nt + srow;
    f32x4 kq4 = {0.f, 0.f, 0.f, 0.f}, vq4 = {0.f, 0.f, 0.f, 0.f};
    if (n < t_end) {
      bf16x4 a = *(const bf16x4*)(kf + (size_t)n * 64 + scol);
      bf16x4 c = *(const bf16x4*)(vv + (size_t)n * 64 + scol);
#pragma unroll
      for (int e = 0; e < 4; e++) { kq4[e] = (float)a[e]; vq4[e] = (float)c[e]; }
    }
    *(f32x4*)(skf + srow * 64 + scol) = kq4;
    *(f32x4*)(sv + srow * 64 + scol) = vq4;
    __syncthreads();
#pragma unroll
    for (int t4 = 0; t4 < 16; t4++) {
      f32x4 kq = *(const f32x4*)(skf + t4 * 64 + f0);
      f32x4 vq = *(const f32x4*)(sv + t4 * 64 + e0);
#pragma unroll
      for (int i = 0; i < 4; i++) {
        ks[i] += kq[i];
#pragma unroll
        for (int j = 0; j < 4; j++) acc[i][j] += kq[i] * vq[j];
      }
    }
    __syncthreads();
  }

  float* cp = CTX + (size_t)bh * 4096;
#pragma unroll
  for (int i = 0; i < 4; i++)
#pragma unroll
    for (int j = 0; j < 4; j++) atomicAdd(&cp[(f0 + i) * 64 + e0 + j], acc[i][j]);
  if (e0 == 0) {
#pragma unroll
    for (int i = 0; i < 4; i++) atomicAdd(&KSUM[bh * 64 + f0 + i], ks[i]);
  }
}

// ---------------- K4: out = (qf @ ctx) * (1/(qf . ksum)), write attn(b,n,h*64+e) ----------------
__global__ __launch_bounds__(256) void k_qside(
    const bft* __restrict__ QF, const float* __restrict__ CTX,
    const float* __restrict__ KSUM, bft* __restrict__ ATTN) {
  __shared__ float sqf[128 * 65];
  __shared__ float sctx[64 * 64];
  __shared__ float sks[64];
  const int tid = threadIdx.x;
  const int bh = blockIdx.x;
  const int n0 = blockIdx.y * 128;
  const int ntok = (SEQ - n0 < 128) ? (SEQ - n0) : 128;
  const bft* qf = QF + ((size_t)bh * SEQ + n0) * HD;

#pragma unroll
  for (int i = 0; i < 4; i++) {
    int idx = i * 1024 + tid * 4;
    *(f32x4*)(sctx + idx) = *(const f32x4*)(CTX + (size_t)bh * 4096 + idx);
  }
  if (tid < 64) sks[tid] = KSUM[bh * 64 + tid];

#pragma unroll
  for (int it = 0; it < 4; it++) {
    int c = it * 256 + tid;
    int row = c >> 3;
    int col = (c & 7) << 3;
    if (row < ntok) {
      bf16x8 t = *(const bf16x8*)(qf + (size_t)row * 64 + col);
#pragma unroll
      for (int e = 0; e < 8; e++) sqf[row * 65 + col + e] = (float)t[e];
    } else {
#pragma unroll
      for (int e = 0; e < 8; e++) sqf[row * 65 + col + e] = 0.f;
    }
  }
  __syncthreads();

  const int e0 = (tid & 7) * 8;
  const int t0 = (tid >> 3) * 4;
  float acc[4][8] = {};
  float den[4] = {0.f, 0.f, 0.f, 0.f};
#pragma unroll 8
  for (int f = 0; f < 64; f++) {
    float kv = sks[f];
    f32x4 c0 = *(const f32x4*)(sctx + f * 64 + e0);
    f32x4 c1 = *(const f32x4*)(sctx + f * 64 + e0 + 4);
#pragma unroll
    for (int tk = 0; tk < 4; tk++) {
      float qv = sqf[(t0 + tk) * 65 + f];
      den[tk] += qv * kv;
      acc[tk][0] += qv * c0[0];
      acc[tk][1] += qv * c0[1];
      acc[tk][2] += qv * c0[2];
      acc[tk][3] += qv * c0[3];
      acc[tk][4] += qv * c1[0];
      acc[tk][5] += qv * c1[1];
      acc[tk][6] += qv * c1[2];
      acc[tk][7] += qv * c1[3];
    }
  }
  const int b = bh / NH;
  const int h = bh - b * NH;
#pragma unroll
  for (int tk = 0; tk < 4; tk++) {
    int n = n0 + t0 + tk;
    if (n < SEQ) {
      float di = 1.0f / den[tk];
      bf16x8 o;
#pragma unroll
      for (int e = 0; e < 8; e++) o[e] = (bft)(acc[tk][e] * di);
      *(bf16x8*)(ATTN + ((size_t)(b * SEQ + n)) * DMODEL + h * 64 + e0) = o;
    }
  }
}

// ---------------- K5: out GEMM (M=32800, N=768, K=768) + bias, fp32 out ----------------
__global__ __launch_bounds__(256) void k_out_gemm(
    const bft* __restrict__ A, const bft* __restrict__ W,
    const float* __restrict__ BIAS, float* __restrict__ OUT) {
  __shared__ __align__(16) bft sA[128 * 64];
  __shared__ __align__(16) bft sB[128 * 64];
  const int tid = threadIdx.x;
  const int lane = tid & 63;
  const int lm = lane & 15;
  const int quad = lane >> 4;
  const int wid = tid >> 6;
  const int wm = (wid & 1) << 6;
  const int wn = (wid >> 1) << 6;
  const int m0 = blockIdx.x * 128;
  const int n0 = blockIdx.y * 128;
  const int sw = lm & 7;
  const int o0 = (quad ^ sw) << 3;
  const int o1 = ((4 + quad) ^ sw) << 3;

  f32x4 acc[4][4] = {};

  for (int kt = 0; kt < DMODEL; kt += 64) {
#pragma unroll
    for (int it = 0; it < 4; it++) {
      int c = it * 256 + tid;
      int row = c >> 3;
      int col = ((c & 7) ^ (row & 7)) << 3;
      int ar = m0 + row;
      if (ar >= MROWS) ar = MROWS - 1;
      gl_lds16(A + (size_t)ar * DMODEL + kt + col, sA + c * 8);
      gl_lds16(W + (size_t)(n0 + row) * DMODEL + kt + col, sB + c * 8);
    }
    __syncthreads();
#pragma unroll
    for (int kk = 0; kk < 2; kk++) {
      const int off = kk ? o1 : o0;
      bf16x8 af[4], bb[4];
#pragma unroll
      for (int i = 0; i < 4; i++)
        af[i] = *(const bf16x8*)(sA + (wm + i * 16 + lm) * 64 + off);
#pragma unroll
      for (int j = 0; j < 4; j++)
        bb[j] = *(const bf16x8*)(sB + (wn + j * 16 + lm) * 64 + off);
#pragma unroll
      for (int i = 0; i < 4; i++)
#pragma unroll
        for (int j = 0; j < 4; j++)
          acc[i][j] = __builtin_amdgcn_mfma_f32_16x16x32_bf16(af[i], bb[j], acc[i][j], 0, 0, 0);
    }
    __syncthreads();
  }

#pragma unroll
  for (int i = 0; i < 4; i++) {
#pragma unroll
    for (int r = 0; r < 4; r++) {
      int m = m0 + wm + i * 16 + quad * 4 + r;
      if (m < MROWS) {
#pragma unroll
        for (int j = 0; j < 4; j++) {
          int g = n0 + wn + j * 16 + lm;
          OUT[(size_t)m * DMODEL + g] = acc[i][j][r] + BIAS[g];
        }
      }
    }
  }
}

extern "C" void kernel_launch(void* const* d_in, const int* in_sizes, int n_in,
                              void* d_out, int out_size, void* d_ws, size_t ws_size,
                              hipStream_t stream) {
  const float* x = (const float*)d_in[0];
  const float* wqkv = (const float*)d_in[1];
  const float* wout = (const float*)d_in[2];
  const float* bout = (const float*)d_in[3];
  const float* proj = (const float*)d_in[4];
  const float* fc = (const float*)d_in[5];
  const float* fs = (const float*)d_in[6];
  float* outp = (float*)d_out;

  // workspace layout (bytes, all 16B-aligned)
  char* ws = (char*)d_ws;
  const size_t xb_bytes = (size_t)MROWS * DMODEL * 2;               // 50,457,600
  const size_t qkv_bytes = (size_t)3 * BHN * SEQ * HD * 2;          // 151,142,400
  const size_t wqkvb_bytes = (size_t)3 * DMODEL * DMODEL * 2;       // 3,538,944
  const size_t woutb_bytes = (size_t)DMODEL * DMODEL * 2;           // 1,179,648
  const size_t projb_bytes = (size_t)HD * HD * 2;                   // 8,192
  const size_t ctx_bytes = (size_t)BHN * 64 * 64 * 4;               // 6,291,456
  const size_t ks_bytes = (size_t)BHN * 64 * 4;                     // 98,304

  bft* xb = (bft*)ws;  // dead after K1 -> reused as attn
  bft* qkvb = (bft*)(ws + xb_bytes);
  bft* wqkvb = (bft*)(ws + xb_bytes + qkv_bytes);
  bft* woutb = (bft*)(ws + xb_bytes + qkv_bytes + wqkvb_bytes);
  bft* projb = (bft*)(ws + xb_bytes + qkv_bytes + wqkvb_bytes + woutb_bytes);
  float* ctx = (float*)(ws + xb_bytes + qkv_bytes + wqkvb_bytes + woutb_bytes + projb_bytes);
  float* ksum = (float*)(ws + xb_bytes + qkv_bytes + wqkvb_bytes + woutb_bytes + projb_bytes + ctx_bytes);
  bft* attn = xb;

  bft* qreg = qkvb;  // holds qf after fused K1
  bft* kreg = qkvb + (size_t)BHN * SEQ * HD;  // kf
  bft* vreg = qkvb + (size_t)2 * BHN * SEQ * HD;  // v

  dim3 blk(256);
  // casts
  k_cast<<<dim3((MROWS * DMODEL / 4 + 255) / 256), blk, 0, stream>>>(x, xb, MROWS * DMODEL / 4);
  k_cast<<<dim3((3 * DMODEL * DMODEL / 4 + 255) / 256), blk, 0, stream>>>(wqkv, wqkvb, 3 * DMODEL * DMODEL / 4);
  k_cast<<<dim3((DMODEL * DMODEL / 4 + 255) / 256), blk, 0, stream>>>(wout, woutb, DMODEL * DMODEL / 4);
  k_cast<<<dim3((HD * HD / 4 + 255) / 256), blk, 0, stream>>>(proj, projb, HD * HD / 4);

  // zero ctx + ksum (adjacent) for atomic accumulation
  hipMemsetAsync(ctx, 0, ctx_bytes + ks_bytes, stream);

  k_qkv_gemm<<<dim3(257, 18), blk, 0, stream>>>(xb, wqkvb, projb, fc, fs, qkvb);
  k_context<<<dim3(BHN, CSPLIT), blk, 0, stream>>>(kreg, vreg, ctx, ksum);
  k_qside<<<dim3(BHN, 9), blk, 0, stream>>>(qreg, ctx, ksum, attn);
  k_out_gemm<<<dim3(257, 6), blk, 0, stream>>>(attn, woutb, bout, outp);
  (void)in_sizes; (void)n_in; (void)out_size; (void)ws_size;
}